// Round 1
// baseline (5619.360 us; speedup 1.0000x reference)
//
#include <hip/hip_runtime.h>
#include <math.h>

// Problem constants (from reference)
constexpr int cH  = 256;   // H
constexpr int cS  = 64;    // S (GRU seq len / p-dim)
constexpr int cAN = 16;    // AN
constexpr int cD  = 8;     // D
constexpr int cT  = 32;    // T
constexpr int cN  = 64;    // N (batch)
constexpr int cHG = 770;   // 2 + 3*H
constexpr int cG3 = 2310;  // 3*HG
constexpr int cOW = 338;   // 1+AN+1+H+S output row width

// ---------------------------------------------------------------------------
// One-off: gi_tab[v][j] = emb[v] . w_ih[j,:] + b_ih[j]   (32 x 2310)
// (input-side GRU GEMM collapses to a 32-row table since inputs are embeddings)
__global__ __launch_bounds__(256) void k_gitab(const float* __restrict__ emb,
                                               const float* __restrict__ w_ih,
                                               const float* __restrict__ b_ih,
                                               float* __restrict__ gitab) {
  int v = blockIdx.y;
  int j = blockIdx.x * 256 + threadIdx.x;
  __shared__ float es[cH];
  es[threadIdx.x] = emb[v * cH + threadIdx.x];
  __syncthreads();
  if (j < cG3) {
    float acc = b_ih[j];
    const float* wr = w_ih + (size_t)j * cH;
    #pragma unroll 8
    for (int h = 0; h < cH; ++h) acc += wr[h] * es[h];
    gitab[(size_t)v * cG3 + j] = acc;
  }
}

// One-off: psip[a][h][o] = psi_w[o, h*AN + a]  (coalesced access in tail)
__global__ __launch_bounds__(256) void k_psiperm(const float* __restrict__ psi_w,
                                                 float* __restrict__ psip) {
  int idx = blockIdx.x * 256 + threadIdx.x;      // a*65536 + h*256 + o
  int a = idx >> 16, h = (idx >> 8) & 255, o = idx & 255;
  psip[idx] = psi_w[((size_t)o * cH + h) * cAN + a];
}

// ---------------------------------------------------------------------------
// GRU step s: gh = h_prev @ w_hh^T (+b_hh), fuse gates, write X[:, s, :].
// block = 256 thr = 64 m x 4 kl; grid 193 (k = blk*4+kl over 770).
__global__ __launch_bounds__(256) void k_gru(const float* __restrict__ whh,
                                             const float* __restrict__ bhh,
                                             const float* __restrict__ gitab,
                                             const int* __restrict__ subtasks,
                                             float* __restrict__ X, int s) {
  int tid = threadIdx.x;
  int m = tid & 63, kl = tid >> 6;
  int k = blockIdx.x * 4 + kl;
  __shared__ float hs[64][20];       // [m][k-chunk 16, pad->20 for f4 align]
  __shared__ float wsr[3][4][20];    // [gate][kl][k-chunk]
  float accr = 0.f, accz = 0.f, accn = 0.f;
  if (s > 0) {
    int lrow = tid >> 2, lcol = (tid & 3) * 4;
    for (int kc = 0; kc < cHG; kc += 16) {
      if (kc + 16 <= cHG) {
        float4 hv = *(const float4*)(X + ((size_t)lrow * cS + (s - 1)) * cHG + kc + lcol);
        *(float4*)&hs[lrow][lcol] = hv;
        if (tid < 48) {
          int g = tid >> 4, rr = (tid >> 2) & 3, c4 = tid & 3;
          int kk = blockIdx.x * 4 + rr;
          float4 wv = make_float4(0.f, 0.f, 0.f, 0.f);
          if (kk < cHG) wv = *(const float4*)(whh + ((size_t)g * cHG + kk) * cHG + kc + c4 * 4);
          *(float4*)&wsr[g][rr][c4 * 4] = wv;
        }
      } else {  // tail chunk (kc=768): guarded scalar loads
        #pragma unroll
        for (int q = 0; q < 4; ++q) {
          int cc = lcol + q;
          hs[lrow][cc] = (kc + cc < cHG) ? X[((size_t)lrow * cS + (s - 1)) * cHG + kc + cc] : 0.f;
        }
        if (tid < 192) {
          int g = tid >> 6, rr = (tid >> 4) & 3, c = tid & 15;
          int kk = blockIdx.x * 4 + rr;
          wsr[g][rr][c] = (kk < cHG && kc + c < cHG)
                              ? whh[((size_t)g * cHG + kk) * cHG + kc + c] : 0.f;
        }
      }
      __syncthreads();
      #pragma unroll
      for (int c4 = 0; c4 < 4; ++c4) {
        float4 hv = *(const float4*)&hs[m][c4 * 4];
        float4 w0 = *(const float4*)&wsr[0][kl][c4 * 4];
        float4 w1 = *(const float4*)&wsr[1][kl][c4 * 4];
        float4 w2 = *(const float4*)&wsr[2][kl][c4 * 4];
        accr += hv.x * w0.x + hv.y * w0.y + hv.z * w0.z + hv.w * w0.w;
        accz += hv.x * w1.x + hv.y * w1.y + hv.z * w1.z + hv.w * w1.w;
        accn += hv.x * w2.x + hv.y * w2.y + hv.z * w2.z + hv.w * w2.w;
      }
      __syncthreads();
    }
  }
  if (k < cHG) {
    int v = subtasks[m * cS + s];
    const float* git = gitab + (size_t)v * cG3;
    float rg = 1.f / (1.f + expf(-(git[k]           + accr + bhh[k])));
    float zg = 1.f / (1.f + expf(-(git[cHG + k]     + accz + bhh[cHG + k])));
    float ng = tanhf(git[2 * cHG + k] + rg * (accn + bhh[2 * cHG + k]));
    float hp = (s > 0) ? X[((size_t)m * cS + (s - 1)) * cHG + k] : 0.f;
    X[((size_t)m * cS + s) * cHG + k] = (1.f - zg) * ng + zg * hp;
  }
}

// ---------------------------------------------------------------------------
// p_init + precompute ||Mp[n,s]||, ||Mm[n,s]|| (constant over the T-scan)
__global__ __launch_bounds__(256) void k_pinit(const float* __restrict__ hxs,
                                               const float* __restrict__ X,
                                               float* __restrict__ p,
                                               float* __restrict__ nMp,
                                               float* __restrict__ nMm) {
  int n = blockIdx.x, tid = threadIdx.x;
  __shared__ int anynz;
  if (tid == 0) anynz = 0;
  __syncthreads();
  int nz = (hxs[n * cOW + tid] != 0.f) ? 1 : 0;
  if (tid + 256 < cOW) nz |= (hxs[n * cOW + tid + 256] != 0.f) ? 1 : 0;
  if (nz) anynz = 1;
  __syncthreads();
  bool newep = (anynz == 0);
  if (tid < cS) {
    const float* xr = X + ((size_t)n * cS + tid) * cHG;
    float p0 = xr[1];
    p[n * cS + tid] = newep ? p0 : hxs[n * cOW + 1 + cAN + 1 + cH + tid];
    float sp = 0.f, sm = 0.f;
    for (int h = 0; h < cH; ++h) {
      float vp = xr[2 + 2 * cH + h]; sp += vp * vp;
      float vm = xr[2 + cH + h];     sm += vm * vm;
    }
    nMp[n * cS + tid] = sqrtf(sp);
    nMm[n * cS + tid] = sqrtf(sm);
  }
}

// ---------------------------------------------------------------------------
// Per step: ps = softmax(p[n]), r[n] = ps @ M[n]
__global__ __launch_bounds__(256) void k_rsoft(const float* __restrict__ p,
                                               const float* __restrict__ X,
                                               float* __restrict__ ps,
                                               float* __restrict__ r) {
  int n = blockIdx.x, tid = threadIdx.x;
  __shared__ float pss[cS];
  __shared__ float red[cS];
  __shared__ float mx, sm;
  if (tid < cS) red[tid] = p[n * cS + tid];
  __syncthreads();
  if (tid == 0) { float m = red[0]; for (int i = 1; i < cS; ++i) m = fmaxf(m, red[i]); mx = m; }
  __syncthreads();
  if (tid < cS) red[tid] = expf(red[tid] - mx);
  __syncthreads();
  if (tid == 0) { float s = 0.f; for (int i = 0; i < cS; ++i) s += red[i]; sm = s; }
  __syncthreads();
  if (tid < cS) { pss[tid] = red[tid] / sm; ps[n * cS + tid] = pss[tid]; }
  __syncthreads();
  float acc = 0.f;
  for (int s2 = 0; s2 < cS; ++s2)
    acc += pss[s2] * X[((size_t)n * cS + s2) * cHG + 2 + tid];
  r[n * cH + tid] = acc;
}

// ---------------------------------------------------------------------------
// conv0 factorized: W0r[o,d] = sum_h conv0_w[o,h*8+d]*r[n,h];
// x1[n,ij,o] = relu(sum_d W0r[o,d]*base[t,n,d,ij] + b0[o]). grid (8 ob, 64 n)
__global__ __launch_bounds__(256) void k_conv0(const float* __restrict__ r,
                                               const float* __restrict__ base,
                                               const float* __restrict__ cw,
                                               const float* __restrict__ cb,
                                               float* __restrict__ x1, int t) {
  int ob = blockIdx.x, n = blockIdx.y, tid = threadIdx.x;
  __shared__ float rs[cH];
  __shared__ float bs[cD * 64];
  __shared__ float wt[32][260];
  __shared__ float w0s[32][9];
  rs[tid] = r[n * cH + tid];
  bs[tid]       = base[((size_t)t * cN + n) * cD * 64 + tid];
  bs[tid + 256] = base[((size_t)t * cN + n) * cD * 64 + tid + 256];
  __syncthreads();
  int o_l = tid >> 3, d = tid & 7;
  float acc = 0.f;
  for (int hc = 0; hc < 8; ++hc) {
    #pragma unroll
    for (int q = 0; q < 8; ++q) {
      int idx = q * 256 + tid;
      int row = idx >> 6, c4 = (idx & 63) * 4;
      *(float4*)&wt[row][c4] =
          *(const float4*)(cw + (size_t)(ob * 32 + row) * (cD * cH) + hc * 256 + c4);
    }
    __syncthreads();
    #pragma unroll
    for (int h2 = 0; h2 < 32; ++h2)
      acc += wt[o_l][h2 * 8 + d] * rs[hc * 32 + h2];
    __syncthreads();
  }
  w0s[o_l][d] = acc;
  __syncthreads();
  int o2 = tid & 31, ijg = tid >> 5;
  float bias = cb[ob * 32 + o2];
  #pragma unroll
  for (int q = 0; q < 8; ++q) {
    int ij = ijg * 8 + q;
    float v = bias;
    #pragma unroll
    for (int d2 = 0; d2 < 8; ++d2) v += w0s[o2][d2] * bs[d2 * 64 + ij];
    x1[((size_t)n * 64 + ij) * cH + ob * 32 + o2] = fmaxf(v, 0.f);
  }
}

// ---------------------------------------------------------------------------
// 1x1 conv GEMM: C(4096,256) = relu(A(4096,256) @ W(256,256)^T + b)
// grid (nb=4, mb=64), block 256, 64x64 tile, 4x4 micro.
// mode 0: row-major out (n,ij,o);  mode 1: write x3t[n, o*64+ij] (lin K-order)
__global__ __launch_bounds__(256) void k_gemm_conv(const float* __restrict__ A,
                                                   const float* __restrict__ W,
                                                   const float* __restrict__ bias,
                                                   float* __restrict__ C, int mode) {
  int nb = blockIdx.x, mb = blockIdx.y, tid = threadIdx.x;
  int tm = tid & 15, tj = tid >> 4;
  __shared__ float As[16][68];
  __shared__ float Bs[16][68];
  float acc[4][4] = {{0.f}};
  int lrow = tid >> 2, lcol = (tid & 3) * 4;
  for (int kc = 0; kc < cH; kc += 16) {
    float4 av = *(const float4*)(A + (size_t)(mb * 64 + lrow) * cH + kc + lcol);
    float4 wv = *(const float4*)(W + (size_t)(nb * 64 + lrow) * cH + kc + lcol);
    As[lcol][lrow] = av.x; As[lcol + 1][lrow] = av.y; As[lcol + 2][lrow] = av.z; As[lcol + 3][lrow] = av.w;
    Bs[lcol][lrow] = wv.x; Bs[lcol + 1][lrow] = wv.y; Bs[lcol + 2][lrow] = wv.z; Bs[lcol + 3][lrow] = wv.w;
    __syncthreads();
    #pragma unroll
    for (int kk = 0; kk < 16; ++kk) {
      float4 a4 = *(const float4*)&As[kk][tm * 4];
      float4 b4 = *(const float4*)&Bs[kk][tj * 4];
      acc[0][0] += a4.x * b4.x; acc[0][1] += a4.x * b4.y; acc[0][2] += a4.x * b4.z; acc[0][3] += a4.x * b4.w;
      acc[1][0] += a4.y * b4.x; acc[1][1] += a4.y * b4.y; acc[1][2] += a4.y * b4.z; acc[1][3] += a4.y * b4.w;
      acc[2][0] += a4.z * b4.x; acc[2][1] += a4.z * b4.y; acc[2][2] += a4.z * b4.z; acc[2][3] += a4.z * b4.w;
      acc[3][0] += a4.w * b4.x; acc[3][1] += a4.w * b4.y; acc[3][2] += a4.w * b4.z; acc[3][3] += a4.w * b4.w;
    }
    __syncthreads();
  }
  if (mode == 0) {
    #pragma unroll
    for (int i = 0; i < 4; ++i) {
      int m = mb * 64 + tm * 4 + i;
      float4 o4;
      o4.x = fmaxf(acc[i][0] + bias[nb * 64 + tj * 4 + 0], 0.f);
      o4.y = fmaxf(acc[i][1] + bias[nb * 64 + tj * 4 + 1], 0.f);
      o4.z = fmaxf(acc[i][2] + bias[nb * 64 + tj * 4 + 2], 0.f);
      o4.w = fmaxf(acc[i][3] + bias[nb * 64 + tj * 4 + 3], 0.f);
      *(float4*)(C + (size_t)m * cH + nb * 64 + tj * 4) = o4;
    }
  } else {
    #pragma unroll
    for (int j = 0; j < 4; ++j) {
      int o = nb * 64 + tj * 4 + j;
      float bv = bias[o];
      float4 o4;
      o4.x = fmaxf(acc[0][j] + bv, 0.f);
      o4.y = fmaxf(acc[1][j] + bv, 0.f);
      o4.z = fmaxf(acc[2][j] + bv, 0.f);
      o4.w = fmaxf(acc[3][j] + bv, 0.f);
      *(float4*)(C + (size_t)mb * (64 * cH) + (size_t)o * 64 + tm * 4) = o4;
    }
  }
}

// ---------------------------------------------------------------------------
// lin split-K: part[kcb][n][o] = sum over K-chunk of x3t(64,16384)@lin_w(256,16384)^T
// grid (nb=4, kcb=64)
__global__ __launch_bounds__(256) void k_lin(const float* __restrict__ A,
                                             const float* __restrict__ W,
                                             float* __restrict__ part) {
  int nb = blockIdx.x, kcb = blockIdx.y, tid = threadIdx.x;
  int tm = tid & 15, tj = tid >> 4;
  __shared__ float As[16][68];
  __shared__ float Bs[16][68];
  float acc[4][4] = {{0.f}};
  int lrow = tid >> 2, lcol = (tid & 3) * 4;
  for (int kc = 0; kc < 256; kc += 16) {
    float4 av = *(const float4*)(A + (size_t)lrow * 16384 + kcb * 256 + kc + lcol);
    float4 wv = *(const float4*)(W + (size_t)(nb * 64 + lrow) * 16384 + kcb * 256 + kc + lcol);
    As[lcol][lrow] = av.x; As[lcol + 1][lrow] = av.y; As[lcol + 2][lrow] = av.z; As[lcol + 3][lrow] = av.w;
    Bs[lcol][lrow] = wv.x; Bs[lcol + 1][lrow] = wv.y; Bs[lcol + 2][lrow] = wv.z; Bs[lcol + 3][lrow] = wv.w;
    __syncthreads();
    #pragma unroll
    for (int kk = 0; kk < 16; ++kk) {
      float4 a4 = *(const float4*)&As[kk][tm * 4];
      float4 b4 = *(const float4*)&Bs[kk][tj * 4];
      acc[0][0] += a4.x * b4.x; acc[0][1] += a4.x * b4.y; acc[0][2] += a4.x * b4.z; acc[0][3] += a4.x * b4.w;
      acc[1][0] += a4.y * b4.x; acc[1][1] += a4.y * b4.y; acc[1][2] += a4.y * b4.z; acc[1][3] += a4.y * b4.w;
      acc[2][0] += a4.z * b4.x; acc[2][1] += a4.z * b4.y; acc[2][2] += a4.z * b4.z; acc[2][3] += a4.z * b4.w;
      acc[3][0] += a4.w * b4.x; acc[3][1] += a4.w * b4.y; acc[3][2] += a4.w * b4.z; acc[3][3] += a4.w * b4.w;
    }
    __syncthreads();
  }
  #pragma unroll
  for (int i = 0; i < 4; ++i) {
    int n = tm * 4 + i;
    float4 o4 = make_float4(acc[i][0], acc[i][1], acc[i][2], acc[i][3]);
    *(float4*)(part + ((size_t)kcb * cN + n) * cH + nb * 64 + tj * 4) = o4;
  }
}

// ---------------------------------------------------------------------------
// Tail per (t,n): reduce lin partials -> s; actor/probs; e=psi; cos; p_new; v; write row.
__global__ __launch_bounds__(256) void k_tail(const float* __restrict__ part,
                                              const float* __restrict__ lin_b,
                                              const float* __restrict__ actor_w,
                                              const float* __restrict__ actor_b,
                                              const float* __restrict__ critic_w,
                                              const float* __restrict__ critic_b,
                                              const float* __restrict__ psip,
                                              const float* __restrict__ psi_b,
                                              const float* __restrict__ inter,
                                              const int* __restrict__ actions,
                                              const float* __restrict__ X,
                                              const float* __restrict__ ps,
                                              const float* __restrict__ nMp,
                                              const float* __restrict__ nMm,
                                              float* __restrict__ p,
                                              float* __restrict__ out, int t) {
  int n = blockIdx.x, tid = threadIdx.x;
  __shared__ float ss[cH];
  __shared__ float es[cH];
  __shared__ float lg[cAN], dp[cAN], nzv[cAN], prb[cAN];
  __shared__ float red[256];
  __shared__ float enorm_s;
  float* orow = out + ((size_t)t * cN + n) * cOW;
  // s = relu(sum_k part + lin_b)
  float acc = lin_b[tid];
  for (int kc = 0; kc < 64; ++kc) acc += part[((size_t)kc * cN + n) * cH + tid];
  float sv = fmaxf(acc, 0.f);
  ss[tid] = sv;
  orow[1 + cAN + 1 + tid] = sv;
  __syncthreads();
  // actor -> probs
  if (tid < cAN) {
    float a = actor_b[tid];
    const float* wr = actor_w + tid * cH;
    for (int h = 0; h < cH; ++h) a += wr[h] * ss[h];
    lg[tid] = a;
  }
  __syncthreads();
  if (tid < cAN) {
    float m = lg[0];
    for (int i = 1; i < cAN; ++i) m = fmaxf(m, lg[i]);
    dp[tid] = expf(lg[tid] - m);
  }
  __syncthreads();
  if (tid < cAN) {
    float s = 0.f;
    for (int i = 0; i < cAN; ++i) s += dp[i];
    float dprob = dp[tid] / s;
    float nv = (tid < 5) ? 1.f : inter[((size_t)t * cN + n) * (cAN - 5) + (tid - 5)];
    nzv[tid] = nv;
    prb[tid] = dprob * nv;
  }
  __syncthreads();
  if (tid < cAN) {
    float sp = 0.f, sn = 0.f;
    for (int i = 0; i < cAN; ++i) { sp += prb[i]; sn += nzv[i]; }
    float deficit = 1.f - sp;
    float v2 = prb[tid] + (nzv[tid] / fmaxf(sn, 1e-12f)) * deficit;
    prb[tid] = fminf(fmaxf(v2, 0.f), 1.f);
  }
  __syncthreads();
  if (tid < cAN) {
    float s = 0.f;
    for (int i = 0; i < cAN; ++i) s += prb[i];
    orow[1 + tid] = prb[tid] / fmaxf(s, 1e-12f);
  }
  // e = psi(s, a_t)
  int at = actions[t * cN + n];
  {
    float a = psi_b[tid];
    for (int h = 0; h < cH; ++h) a += psip[((size_t)at * cH + h) * cH + tid] * ss[h];
    es[tid] = a;
    red[tid] = a * a;
  }
  __syncthreads();
  for (int st = 128; st > 0; st >>= 1) {
    if (tid < st) red[tid] += red[tid + st];
    __syncthreads();
  }
  if (tid == 0) enorm_s = sqrtf(red[0]);
  __syncthreads();
  float enorm = enorm_s;
  // v (critic), a_t
  if (tid == 0) {
    float a = critic_b[0];
    for (int h = 0; h < cH; ++h) a += critic_w[h] * ss[h];
    orow[1 + cAN] = a;
    orow[0] = (float)at;
  }
  // cos + p_new
  if (tid < cS) {
    const float* xr = X + ((size_t)n * cS + tid) * cHG;
    float dpp = 0.f, dmm = 0.f;
    for (int h = 0; h < cH; ++h) {
      float ev = es[h];
      dpp += ev * xr[2 + 2 * cH + h];
      dmm += ev * xr[2 + cH + h];
    }
    float cP = dpp / fmaxf(enorm * nMp[n * cS + tid], 1e-8f);
    float cM = dmm / fmaxf(enorm * nMm[n * cS + tid], 1e-8f);
    float cc = xr[0];
    float pn = ps[n * cS + tid] + cc * cP - cc * cM;
    p[n * cS + tid] = pn;
    orow[1 + cAN + 1 + cH + tid] = pn;
  }
  // second output (hx_out[-1:]) at t == T-1
  if (t == cT - 1) {
    __threadfence_block();
    __syncthreads();
    float* orow2 = out + (size_t)cT * cN * cOW + (size_t)n * cOW;
    orow2[tid] = orow[tid];
    if (tid + 256 < cOW) orow2[tid + 256] = orow[tid + 256];
  }
}

// ---------------------------------------------------------------------------
extern "C" void kernel_launch(void* const* d_in, const int* in_sizes, int n_in,
                              void* d_out, int out_size, void* d_ws, size_t ws_size,
                              hipStream_t stream) {
  const float* base     = (const float*)d_in[0];
  const float* inter    = (const float*)d_in[1];
  const float* hxs      = (const float*)d_in[2];
  const float* emb      = (const float*)d_in[3];
  const float* w_ih     = (const float*)d_in[4];
  const float* w_hh     = (const float*)d_in[5];
  const float* b_ih     = (const float*)d_in[6];
  const float* b_hh     = (const float*)d_in[7];
  const float* conv0_w  = (const float*)d_in[8];
  const float* conv0_b  = (const float*)d_in[9];
  const float* convs_w  = (const float*)d_in[10];
  const float* convs_b  = (const float*)d_in[11];
  const float* lin_w    = (const float*)d_in[12];
  const float* lin_b    = (const float*)d_in[13];
  const float* psi_w    = (const float*)d_in[14];
  const float* psi_b    = (const float*)d_in[15];
  const float* actor_w  = (const float*)d_in[16];
  const float* actor_b  = (const float*)d_in[17];
  const float* critic_w = (const float*)d_in[18];
  const float* critic_b = (const float*)d_in[19];
  const int*   subtasks = (const int*)d_in[20];
  const int*   actions  = (const int*)d_in[21];
  float* out = (float*)d_out;
  float* ws  = (float*)d_ws;

  // ws layout (floats); total 7,454,912 floats ~= 29.9 MB
  float* gitab = ws + 0;         // 73920
  float* X     = ws + 73920;     // 3,153,920
  float* psip  = ws + 3227840;   // 1,048,576
  float* p     = ws + 4276416;   // 4096
  float* psb   = ws + 4280512;   // 4096
  float* r     = ws + 4284608;   // 16384
  float* nMp   = ws + 4300992;   // 4096
  float* nMm   = ws + 4305088;   // 4096
  float* x1    = ws + 4309184;   // 1,048,576  (aliased by lin partials)
  float* part  = x1;             //   x1 is dead by the time k_lin writes
  float* x2    = ws + 5357760;   // 1,048,576
  float* x3t   = ws + 6406336;   // 1,048,576

  k_gitab<<<dim3(10, 32), 256, 0, stream>>>(emb, w_ih, b_ih, gitab);
  k_psiperm<<<4096, 256, 0, stream>>>(psi_w, psip);
  for (int s = 0; s < cS; ++s)
    k_gru<<<193, 256, 0, stream>>>(w_hh, b_hh, gitab, subtasks, X, s);
  k_pinit<<<64, 256, 0, stream>>>(hxs, X, p, nMp, nMm);
  for (int t = 0; t < cT; ++t) {
    k_rsoft<<<64, 256, 0, stream>>>(p, X, psb, r);
    k_conv0<<<dim3(8, 64), 256, 0, stream>>>(r, base, conv0_w, conv0_b, x1, t);
    k_gemm_conv<<<dim3(4, 64), 256, 0, stream>>>(x1, convs_w, convs_b, x2, 0);
    k_gemm_conv<<<dim3(4, 64), 256, 0, stream>>>(x2, convs_w + 65536, convs_b + 256, x3t, 1);
    k_lin<<<dim3(4, 64), 256, 0, stream>>>(x3t, lin_w, part);
    k_tail<<<64, 256, 0, stream>>>(part, lin_b, actor_w, actor_b, critic_w, critic_b,
                                   psip, psi_b, inter, actions, X, psb, nMp, nMm,
                                   p, out, t);
  }
}